// Round 1
// baseline (7271.389 us; speedup 1.0000x reference)
//
#include <hip/hip_runtime.h>
#include <math.h>

#define B_  512
#define T_  200
#define D_  256
#define H_  256
#define KK  (D_ + H_)      // 512, concat length
#define ROWS 4             // batch rows per block
#define NBLK (B_ / ROWS)   // 128 blocks
#define NTH 1024

__device__ __forceinline__ float sigmoid_f(float x) {
    return 1.0f / (1.0f + __expf(-x));
}
__device__ __forceinline__ float tanh_f(float x) {
    // 1 - 2/(e^{2x}+1): saturates cleanly at +/-1, no inf/inf NaN
    return 1.0f - 2.0f / (__expf(2.0f * x) + 1.0f);
}

__global__ __launch_bounds__(NTH, 1) void gru_persist(
    const float* __restrict__ x,    // [B, T, D]
    const int*   __restrict__ slen, // [B, 1]
    const float* __restrict__ gk,   // [512, 512] (reset|update)
    const float* __restrict__ gb,   // [512]
    const float* __restrict__ ck,   // [512, 256]
    const float* __restrict__ cb,   // [256]
    float* __restrict__ out)        // [B, T, H]
{
    __shared__ __align__(16) float xh[ROWS][KK];  // [x | h]
    __shared__ __align__(16) float xc[ROWS][KK];  // [x | r*h]
    __shared__ float ul[ROWS][H_];                // u gate

    const int tid  = threadIdx.x;
    const int b0   = blockIdx.x * ROWS;
    const int row  = tid >> 8;        // 0..3  (for x-load / candidate / update)
    const int col  = tid & 255;       // 0..255
    const int pr   = (tid >> 9) * 2;  // 0 or 2 (row pair for gates)
    const int gcol = tid & 511;       // 0..511 gate column

    // init h = 0
    xh[row][D_ + col] = 0.0f;

    const int   len   = slen[b0 + row];
    const float gbias = gb[gcol];
    const float cbias = cb[col];

    for (int t = 0; t < T_; ++t) {
        __syncthreads();   // protect h writes of prev step vs reads below
        // ---- load x_t for our 4 rows ----
        float xv = x[((size_t)(b0 + row) * T_ + t) * D_ + col];
        xh[row][col] = xv;
        xc[row][col] = xv;
        __syncthreads();

        // ---- gates: each thread does gate column gcol for rows pr, pr+1 ----
        float a0 = 0.0f, a1 = 0.0f;
        {
            const float*  wg = gk + gcol;
            const float4* v0 = (const float4*)xh[pr];
            const float4* v1 = (const float4*)xh[pr + 1];
            #pragma unroll 2
            for (int k = 0; k < KK; k += 4) {
                float4 p0 = v0[k >> 2];
                float4 p1 = v1[k >> 2];
                float w0 = wg[(size_t)(k + 0) * 512];
                float w1 = wg[(size_t)(k + 1) * 512];
                float w2 = wg[(size_t)(k + 2) * 512];
                float w3 = wg[(size_t)(k + 3) * 512];
                a0 = fmaf(p0.x, w0, a0); a0 = fmaf(p0.y, w1, a0);
                a0 = fmaf(p0.z, w2, a0); a0 = fmaf(p0.w, w3, a0);
                a1 = fmaf(p1.x, w0, a1); a1 = fmaf(p1.y, w1, a1);
                a1 = fmaf(p1.z, w2, a1); a1 = fmaf(p1.w, w3, a1);
            }
        }
        a0 = sigmoid_f(a0 + gbias);
        a1 = sigmoid_f(a1 + gbias);
        if (gcol < D_) {   // reset gate -> stage r*h for candidate matmul
            xc[pr    ][D_ + gcol] = a0 * xh[pr    ][D_ + gcol];
            xc[pr + 1][D_ + gcol] = a1 * xh[pr + 1][D_ + gcol];
        } else {           // update gate -> stage u
            ul[pr    ][gcol - D_] = a0;
            ul[pr + 1][gcol - D_] = a1;
        }
        __syncthreads();

        // ---- candidate: each thread does column col for its row ----
        float a = 0.0f;
        {
            const float*  wc = ck + col;
            const float4* vv = (const float4*)xc[row];
            #pragma unroll 2
            for (int k = 0; k < KK; k += 4) {
                float4 p = vv[k >> 2];
                a = fmaf(p.x, wc[(size_t)(k + 0) * 256], a);
                a = fmaf(p.y, wc[(size_t)(k + 1) * 256], a);
                a = fmaf(p.z, wc[(size_t)(k + 2) * 256], a);
                a = fmaf(p.w, wc[(size_t)(k + 3) * 256], a);
            }
        }
        a = tanh_f(a + cbias);

        const float hold = xh[row][D_ + col];
        const float u    = ul[row][col];
        const float hnew = u * hold + (1.0f - u) * a;
        const bool  valid = (t < len);

        out[((size_t)(b0 + row) * T_ + t) * H_ + col] = valid ? hnew : 0.0f;
        if (valid) xh[row][D_ + col] = hnew;   // freeze h past seq_len
    }
}

extern "C" void kernel_launch(void* const* d_in, const int* in_sizes, int n_in,
                              void* d_out, int out_size, void* d_ws, size_t ws_size,
                              hipStream_t stream) {
    const float* x    = (const float*)d_in[0];
    const int*   slen = (const int*)  d_in[1];
    const float* gk   = (const float*)d_in[2];
    const float* gb   = (const float*)d_in[3];
    const float* ck   = (const float*)d_in[4];
    const float* cb   = (const float*)d_in[5];
    float* out = (float*)d_out;

    gru_persist<<<NBLK, NTH, 0, stream>>>(x, slen, gk, gb, ck, cb, out);
}